// Round 5
// baseline (499.150 us; speedup 1.0000x reference)
//
#include <hip/hip_runtime.h>
#include <stdint.h>

typedef __attribute__((ext_vector_type(4))) int i32x4;
typedef __attribute__((ext_vector_type(16))) int i32x16;

// Fragment-order layout shared by quant writers and the GEMM reader:
//   slot16(rb, kc, ks, l) = ((rb*NKC + kc)*2 + ks)*64 + l     (16-byte units)
// rb = 32-row block, kc = 64-byte K-chunk (NKC = K/64), ks = K-half (32B),
// l = fh*32 + fl: lane fh*32+fl holds bytes [row rb*32+fl][k = kc*64 + ks*32 + fh*16 .. +16)
// -> exactly the A/B operand of mfma_i32_32x32x32_i8. GEMM loads are
// wave-contiguous 1KB bursts; no LDS staging needed at all.

// ---------------- blend: blended[g] = sum_p routing[p] * ps[p*G+g] ----------
__global__ void blend_k(const float* __restrict__ ps, const float* __restrict__ rt,
                        float* __restrict__ blended, int G, int P) {
  int g = blockIdx.x * blockDim.x + threadIdx.x;
  if (g >= G) return;
  float s = 0.f;
  for (int p = 0; p < P; ++p) s += rt[p] * ps[(size_t)p * G + g];
  blended[g] = s;
}

__device__ __forceinline__ int q8(float v, float s) {
  int q = (int)rintf(v * s);
  q = q > 127 ? 127 : q;
  q = q < -127 ? -127 : q;
  return q & 0xff;
}

__device__ __forceinline__ int pack4(float4 v, float s) {
  return q8(v.x, s) | (q8(v.y, s) << 8) | (q8(v.z, s) << 16) | (q8(v.w, s) << 24);
}

// ---------------- quantize W into fragment order ----------------------------
// One block per 32 output rows. thread t: row r = t>>3, K-segment s = t&7
// (512 weights). Writes int4 per 16 weights at the fragment slot.
__global__ __launch_bounds__(256) void quant_w_k(const float* __restrict__ signs,
                                                 const float* __restrict__ blended,
                                                 int4* __restrict__ wq, int K) {
  const int rb = blockIdx.x;
  const int t = threadIdx.x;
  const int r = t >> 3, s = t & 7;
  const int n = rb * 32 + r;
  const int NKC = K >> 6;
  const float4* sr = (const float4*)(signs + (size_t)n * K + s * 512);
  // group scales: 4 groups of 128 within this 512-segment
  int qv[4];
#pragma unroll
  for (int g = 0; g < 4; ++g) {
    float bl = blended[n * (K >> 7) + s * 4 + g];
    int q = (int)rintf(bl * 127.f);
    qv[g] = q > 127 ? 127 : (q < 1 ? 1 : q);
  }
#pragma unroll 4
  for (int j = 0; j < 32; ++j) {          // 16 weights -> one 16B slot
    const int q = qv[j >> 3];
    int4 o;
#pragma unroll
    for (int u = 0; u < 4; ++u) {
      float4 v = sr[j * 4 + u];
      int b0 = (v.x >= 0.f ? q : -q) & 0xff;
      int b1 = (v.y >= 0.f ? q : -q) & 0xff;
      int b2 = (v.z >= 0.f ? q : -q) & 0xff;
      int b3 = (v.w >= 0.f ? q : -q) & 0xff;
      ((int*)&o)[u] = b0 | (b1 << 8) | (b2 << 16) | (b3 << 24);
    }
    const int kc = s * 8 + (j >> 2);
    const int ks = (j >> 1) & 1;
    const int fh = j & 1;
    wq[((size_t)(rb * NKC + kc) * 2 + ks) * 64 + fh * 32 + r] = o;
  }
}

// ---------------- quantize X into fragment order ----------------------------
// One block per 32 rows of x. thread t: row r = t>>3, segment s = t&7 (512
// floats). Pass 1: row amax (8-lane shfl reduce). Pass 2 (L2-hot): pack.
__global__ __launch_bounds__(256) void quant_x_k(const float* __restrict__ x,
                                                 int4* __restrict__ xq,
                                                 float* __restrict__ rowinv, int K) {
  const int rb = blockIdx.x;
  const int t = threadIdx.x;
  const int r = t >> 3, s = t & 7;
  const int m = rb * 32 + r;
  const int NKC = K >> 6;
  const float4* xr = (const float4*)(x + (size_t)m * K + s * 512);
  float amax = 0.f;
#pragma unroll 8
  for (int i = 0; i < 128; ++i) {
    float4 v = xr[i];
    amax = fmaxf(amax, fmaxf(fmaxf(fabsf(v.x), fabsf(v.y)),
                             fmaxf(fabsf(v.z), fabsf(v.w))));
  }
  amax = fmaxf(amax, __shfl_xor(amax, 1));
  amax = fmaxf(amax, __shfl_xor(amax, 2));
  amax = fmaxf(amax, __shfl_xor(amax, 4));
  const float sc = 127.f / amax;
  if (s == 0) rowinv[m] = amax / (127.f * 127.f);
#pragma unroll 4
  for (int j = 0; j < 32; ++j) {          // 16 floats -> one 16B slot
    int4 o;
#pragma unroll
    for (int u = 0; u < 4; ++u) ((int*)&o)[u] = pack4(xr[j * 4 + u], sc);
    const int kc = s * 8 + (j >> 2);
    const int ks = (j >> 1) & 1;
    const int fh = j & 1;
    xq[((size_t)(rb * NKC + kc) * 2 + ks) * 64 + fh * 32 + r] = o;
  }
}

// ---------------- i8 GEMM, flat (no LDS, no barriers) -----------------------
// C[M,N] = (A[M,K]*B[N,K]^T) * rowinv[m]. Operands pre-arranged in fragment
// order, so every load is a wave-contiguous 1KB dwordx4 burst. 256x128 block
// tile, 4 waves (2x2), per-wave 128x64 = acc[4][2] of 32x32 (128 VGPR).
// ~240 VGPR total -> 2 blocks/CU (2 waves/SIMD): two INDEPENDENT blocks cover
// each other's memory latency -- no workgroup barrier anywhere in the K-loop
// (the invariant that pinned all LDS variants at 36% MfmaUtil). Register
// double-buffer (named a0/b0,a1/b1 - static indexing, rule 20); compiler
// emits counted vmcnt for the in-flight buffer.
#define BM 256
#define BN 128

__global__ __launch_bounds__(256, 2) void gemm_i8_k(
    const signed char* __restrict__ A8, const signed char* __restrict__ B8,
    const float* __restrict__ rowinv, float* __restrict__ C, int M, int N, int K) {
  const int tid  = threadIdx.x;
  const int lane = tid & 63;
  const int wave = tid >> 6;          // 0..3, 2x2

  // bijective XCD swizzle (nwg = 1024, divisible by 8)
  int bid = blockIdx.y * gridDim.x + blockIdx.x;
  const int nwg = gridDim.x * gridDim.y;
  const int cpx = nwg >> 3;
  bid = (bid & 7) * cpx + (bid >> 3);
  const int nbx = N / BN;
  const int bn = (bid % nbx) * BN;
  const int bm = (bid / nbx) * BM;

  const int wm = (wave >> 1) * 128;
  const int wn = (wave & 1) * 64;
  const int fl = lane & 31;
  const int fh = lane >> 5;
  const int NKC = K >> 6;             // 64

  // fragment streams: pA[mi] / pB[ni] point at (rb, kc=0, ks=0, lane)
  const i32x4* pA[4];
  const i32x4* pB[2];
#pragma unroll
  for (int mi = 0; mi < 4; ++mi) {
    const int rb = (bm >> 5) + (wave >> 1) * 4 + mi;
    pA[mi] = (const i32x4*)A8 + (size_t)rb * NKC * 2 * 64 + lane;
  }
#pragma unroll
  for (int ni = 0; ni < 2; ++ni) {
    const int rb = (bn >> 5) + (wave & 1) * 2 + ni;
    pB[ni] = (const i32x4*)B8 + (size_t)rb * NKC * 2 * 64 + lane;
  }

  i32x16 acc[4][2];
#pragma unroll
  for (int i = 0; i < 4; ++i)
#pragma unroll
    for (int j = 0; j < 2; ++j)
#pragma unroll
      for (int r = 0; r < 16; ++r) acc[i][j][r] = 0;

  i32x4 a0[2][4], b0[2][2], a1[2][4], b1[2][2];

#define LOADK(kc, aa, bb)                                                     \
  {                                                                           \
    _Pragma("unroll")                                                         \
    for (int ks_ = 0; ks_ < 2; ++ks_) {                                       \
      _Pragma("unroll")                                                       \
      for (int mi_ = 0; mi_ < 4; ++mi_)                                       \
        aa[ks_][mi_] = pA[mi_][(kc) * 128 + ks_ * 64];                        \
      _Pragma("unroll")                                                       \
      for (int ni_ = 0; ni_ < 2; ++ni_)                                       \
        bb[ks_][ni_] = pB[ni_][(kc) * 128 + ks_ * 64];                        \
    }                                                                         \
  }

#define MM(aa, bb)                                                            \
  {                                                                           \
    __builtin_amdgcn_s_setprio(1);                                            \
    _Pragma("unroll")                                                         \
    for (int ks_ = 0; ks_ < 2; ++ks_)                                         \
      _Pragma("unroll")                                                       \
      for (int mi_ = 0; mi_ < 4; ++mi_)                                       \
        _Pragma("unroll")                                                     \
        for (int ni_ = 0; ni_ < 2; ++ni_)                                     \
          acc[mi_][ni_] = __builtin_amdgcn_mfma_i32_32x32x32_i8(              \
              aa[ks_][mi_], bb[ks_][ni_], acc[mi_][ni_], 0, 0, 0);            \
    __builtin_amdgcn_s_setprio(0);                                            \
  }

  LOADK(0, a0, b0);
  for (int kc = 0; kc < NKC - 2; kc += 2) {
    LOADK(kc + 1, a1, b1);
    MM(a0, b0);
    LOADK(kc + 2, a0, b0);
    MM(a1, b1);
  }
  LOADK(NKC - 1, a1, b1);
  MM(a0, b0);
  MM(a1, b1);
#undef LOADK
#undef MM

  // C/D layout (32x32): col = lane&31, row = (reg&3) + 8*(reg>>2) + 4*(lane>>5)
#pragma unroll
  for (int mi = 0; mi < 4; ++mi) {
    const int rbase = bm + wm + mi * 32 + 4 * fh;
    float ri[16];
#pragma unroll
    for (int r = 0; r < 16; ++r) ri[r] = rowinv[rbase + (r & 3) + 8 * (r >> 2)];
#pragma unroll
    for (int ni = 0; ni < 2; ++ni) {
      const int col = bn + wn + ni * 32 + fl;
#pragma unroll
      for (int r = 0; r < 16; ++r) {
        const int row = rbase + (r & 3) + 8 * (r >> 2);
        C[(size_t)row * N + col] = (float)acc[mi][ni][r] * ri[r];
      }
    }
  }
}

// Safety-net exact fp32 kernel (only if ws_size too small) — slow but correct.
__global__ void naive_k(const float* __restrict__ x, const float* __restrict__ signs,
                        const float* __restrict__ ps, const float* __restrict__ rt,
                        float* __restrict__ out, int M, int N, int K, int P) {
  int idx = blockIdx.x * blockDim.x + threadIdx.x;
  if (idx >= M * N) return;
  int m = idx / N, n = idx % N;
  const float* xr = x + (size_t)m * K;
  const float* wr = signs + (size_t)n * K;
  const int NG = K / 128;
  const size_t G = (size_t)N * NG;
  float acc = 0.f;
  for (int g = 0; g < NG; ++g) {
    float sc = 0.f;
    int gi = n * NG + g;
    for (int p = 0; p < P; ++p) sc += rt[p] * ps[(size_t)p * G + gi];
    float s2 = 0.f;
    for (int kk = 0; kk < 128; ++kk) s2 += xr[g * 128 + kk] * wr[g * 128 + kk];
    acc += sc * s2;
  }
  out[idx] = acc;
}

extern "C" void kernel_launch(void* const* d_in, const int* in_sizes, int n_in,
                              void* d_out, int out_size, void* d_ws, size_t ws_size,
                              hipStream_t stream) {
  const float* x     = (const float*)d_in[0];
  const float* signs = (const float*)d_in[1];
  const float* ps    = (const float*)d_in[2];
  const float* rt    = (const float*)d_in[3];
  float* out = (float*)d_out;

  const int K = 4096, N = 4096, GS = 128;
  const int M = in_sizes[0] / K;   // 8192
  const int G = N / GS * K;        // 131072 flat groups over [N*K]
  const int P = in_sizes[3];       // 8

  const size_t xq_bytes = (size_t)M * K;       // 33.5 MB
  const size_t wq_bytes = (size_t)N * K;       // 16.8 MB
  const size_t bl_bytes = (size_t)G * 4;       // 0.5 MB
  const size_t ri_bytes = (size_t)M * 4;       // 32 KB
  const size_t need = xq_bytes + wq_bytes + bl_bytes + ri_bytes;

  if (ws_size >= need && (M % BM) == 0) {
    signed char* xq = (signed char*)d_ws;
    signed char* wq = (signed char*)((char*)d_ws + xq_bytes);
    float* blended  = (float*)((char*)d_ws + xq_bytes + wq_bytes);
    float* rowinv   = (float*)((char*)d_ws + xq_bytes + wq_bytes + bl_bytes);

    blend_k<<<(G + 255) / 256, 256, 0, stream>>>(ps, rt, blended, G, P);

    quant_w_k<<<N / 32, 256, 0, stream>>>(signs, blended, (int4*)wq, K);

    quant_x_k<<<M / 32, 256, 0, stream>>>(x, (int4*)xq, rowinv, K);

    dim3 grid(N / BN, M / BM);
    gemm_i8_k<<<grid, 256, 0, stream>>>(xq, wq, rowinv, out, M, N, K);
  } else {
    const size_t total = (size_t)M * N;
    naive_k<<<(int)((total + 255) / 256), 256, 0, stream>>>(
        x, signs, ps, rt, out, M, N, K, P);
  }
}

// Round 6
// 422.535 us; speedup vs baseline: 1.1813x; 1.1813x over previous
//
#include <hip/hip_runtime.h>
#include <stdint.h>

#define AS1 __attribute__((address_space(1)))
#define AS3 __attribute__((address_space(3)))

typedef __attribute__((ext_vector_type(4))) int i32x4;
typedef __attribute__((ext_vector_type(16))) int i32x16;

__device__ __forceinline__ int q8(float v, float s) {
  int q = (int)rintf(v * s);
  q = q > 127 ? 127 : q;
  q = q < -127 ? -127 : q;
  return q & 0xff;
}

// ---------------- fused prep: ONE launch for blend + quant_w + quant_x ------
// Blocks [0, NW): W-role. thread t packs 16 weights -> int4 wq[t] (linear
// [n][K/16] layout). Group scale blended inline: g = t>>3,
// bl = sum_p rt[p]*ps[p*G+g] (ps is 4MB -> L2-resident; ~P extra FMAs/thread).
// Blocks [NW, NW+M): X-role. One block per x row: rowmax (wave shfl + LDS
// reduce) then pack to xq (linear [m][K/4] ints), rowinv[m] = amax/127^2.
// Rationale: rounds 0-4 showed ~260us of the 425us total living OUTSIDE the
// gemm across 3 dependency-serialized prep launches; prep ideal is ~45us.
// Fusing to one launch removes two launch gaps + the blended round-trip, and
// makes prep cost visible in top-5 profiling.
__global__ __launch_bounds__(256) void prep_k(
    const float* __restrict__ signs, const float* __restrict__ ps,
    const float* __restrict__ rt, const float* __restrict__ x,
    int4* __restrict__ wq, int* __restrict__ xq, float* __restrict__ rowinv,
    int G, int P, int K, int NW) {
  __shared__ float red[4];
  if ((int)blockIdx.x < NW) {
    // ---- W role: 16 weights/thread ----
    const int t = blockIdx.x * 256 + threadIdx.x;
    const int g = t >> 3;                 // (t*16)>>7: group of 128 weights
    float bl = 0.f;
    for (int p = 0; p < P; ++p) bl += rt[p] * ps[(size_t)p * G + g];
    int q = (int)rintf(bl * 127.f);
    q = q > 127 ? 127 : q; q = q < 1 ? 1 : q;
    const float4* s4 = (const float4*)signs;
    int b[16];
#pragma unroll
    for (int i = 0; i < 4; ++i) {
      float4 s = s4[(size_t)t * 4 + i];
      b[i * 4 + 0] = (s.x >= 0.f ? q : -q) & 0xff;
      b[i * 4 + 1] = (s.y >= 0.f ? q : -q) & 0xff;
      b[i * 4 + 2] = (s.z >= 0.f ? q : -q) & 0xff;
      b[i * 4 + 3] = (s.w >= 0.f ? q : -q) & 0xff;
    }
    int4 o;
    o.x = b[0] | (b[1] << 8) | (b[2] << 16) | (b[3] << 24);
    o.y = b[4] | (b[5] << 8) | (b[6] << 16) | (b[7] << 24);
    o.z = b[8] | (b[9] << 8) | (b[10] << 16) | (b[11] << 24);
    o.w = b[12] | (b[13] << 8) | (b[14] << 16) | (b[15] << 24);
    wq[t] = o;
  } else {
    // ---- X role: one block per row ----
    const int m = blockIdx.x - NW;
    const int t = threadIdx.x;
    const int lane = t & 63;
    const int wave = t >> 6;
    const float4* xr = (const float4*)x + (size_t)m * (K / 4);
    float4 v[4];
    float amax = 0.f;
#pragma unroll
    for (int i = 0; i < 4; ++i) {
      v[i] = xr[t + 256 * i];
      amax = fmaxf(amax, fmaxf(fmaxf(fabsf(v[i].x), fabsf(v[i].y)),
                               fmaxf(fabsf(v[i].z), fabsf(v[i].w))));
    }
#pragma unroll
    for (int off = 1; off < 64; off <<= 1)
      amax = fmaxf(amax, __shfl_xor(amax, off));
    if (lane == 0) red[wave] = amax;
    __syncthreads();
    amax = fmaxf(fmaxf(red[0], red[1]), fmaxf(red[2], red[3]));
    const float s = 127.f / amax;
    if (t == 0) rowinv[m] = amax / (127.f * 127.f);
    int* xo = xq + (size_t)m * (K / 4);
#pragma unroll
    for (int i = 0; i < 4; ++i) {
      int p = q8(v[i].x, s) | (q8(v[i].y, s) << 8) | (q8(v[i].z, s) << 16) |
              (q8(v[i].w, s) << 24);
      xo[t + 256 * i] = p;
    }
  }
}

// ---------------- i8 GEMM: C[M,N] = (A[M,K] * B[N,K]^T) * rowinv[m] ---------
// (reverted to round-3 best: 165.4 us, MfmaUtil 36%)
// 256x256 tile, 8 waves (2Mx4N), per-wave 128x64 via 4x2 of mfma_i32_32x32x32_i8.
// K in 64-byte halves through a 4-deep LDS ring (4 x 32KiB). 2-phase split per
// K-64 with counted vmcnt once per K-64 (never 0 mid-loop). LDS swizzle:
// slot = chunk ^ ((row>>1)&3), applied source-side for the linear
// global_load_lds dest and on the ds_read addr (rule 21).
#define BM 256
#define BN 256

__global__ __launch_bounds__(512, 2) void gemm_i8_k(
    const signed char* __restrict__ A, const signed char* __restrict__ B,
    const float* __restrict__ rowinv, float* __restrict__ C, int M, int N, int K) {
  __shared__ __align__(16) signed char lds[4][2][256 * 64];   // [buf][A/B][row*64+slot*16]
  const int tid  = threadIdx.x;
  const int lane = tid & 63;
  const int wave = tid >> 6;

  // bijective XCD swizzle (nwg = 512, divisible by 8)
  int bid = blockIdx.y * gridDim.x + blockIdx.x;
  const int nwg = gridDim.x * gridDim.y;
  const int cpx = nwg >> 3;
  bid = (bid & 7) * cpx + (bid >> 3);
  const int nbx = N / BN;
  const int bn = (bid % nbx) * BN;
  const int bm = (bid / nbx) * BM;

  const int wm = (wave >> 2) * 128;
  const int wn = (wave & 3) * 64;
  const int fl = lane & 31;
  const int fh = lane >> 5;
  const int sx = (fl >> 1) & 3;   // read-side swizzle: slot = chunk ^ sx

  // loop-invariant LDS read offsets
  int offA[4], offB[2];
#pragma unroll
  for (int mi = 0; mi < 4; ++mi) offA[mi] = (wm + mi * 32 + fl) * 64;
#pragma unroll
  for (int ni = 0; ni < 2; ++ni) offB[ni] = (wn + ni * 32 + fl) * 64;
  const int c0 = ((0 + fh) ^ sx) * 16;   // ks=0 chunk
  const int c1 = ((2 + fh) ^ sx) * 16;   // ks=1 chunk

  i32x16 acc[4][2];
#pragma unroll
  for (int i = 0; i < 4; ++i)
#pragma unroll
    for (int j = 0; j < 2; ++j)
#pragma unroll
      for (int r = 0; r < 16; ++r) acc[i][j][r] = 0;

  // Staging: one global_load_lds = 64 lanes x 16B = 16 rows of 64B (linear
  // dest, lane l -> row R0+(l>>2), slot l&3). Source chunk pre-swizzled:
  // c = (l&3) ^ ((l>>3)&3) so slot s of row r holds chunk s ^ ((r>>1)&3).
  const int sl   = (lane & 3) ^ ((lane >> 3) & 3);
  const int srow = lane >> 2;
  const int rA0 = 16 * (2 * wave + 0) + srow;
  const int rA1 = 16 * (2 * wave + 1) + srow;
  const signed char* gA0 = A + (size_t)(bm + rA0) * K + sl * 16;
  const signed char* gA1 = A + (size_t)(bm + rA1) * K + sl * 16;
  const signed char* gB0 = B + (size_t)(bn + rA0) * K + sl * 16;
  const signed char* gB1 = B + (size_t)(bn + rA1) * K + sl * 16;

#define STAGE(hh)                                                                \
  {                                                                              \
    const int q_  = (hh) & 3;                                                    \
    const int ko_ = (hh) * 64;                                                   \
    __builtin_amdgcn_global_load_lds((AS1 unsigned int*)(gA0 + ko_),             \
        (AS3 unsigned int*)(&lds[q_][0][(2 * wave + 0) * 1024]), 16, 0, 0);      \
    __builtin_amdgcn_global_load_lds((AS1 unsigned int*)(gA1 + ko_),             \
        (AS3 unsigned int*)(&lds[q_][0][(2 * wave + 1) * 1024]), 16, 0, 0);      \
    __builtin_amdgcn_global_load_lds((AS1 unsigned int*)(gB0 + ko_),             \
        (AS3 unsigned int*)(&lds[q_][1][(2 * wave + 0) * 1024]), 16, 0, 0);      \
    __builtin_amdgcn_global_load_lds((AS1 unsigned int*)(gB1 + ko_),             \
        (AS3 unsigned int*)(&lds[q_][1][(2 * wave + 1) * 1024]), 16, 0, 0);      \
  }

  const int NH = K >> 6;   // 64-byte halves of K
  STAGE(0); STAGE(1); STAGE(2);
  asm volatile("s_waitcnt vmcnt(8)" ::: "memory");   // half 0 resident
  __builtin_amdgcn_s_barrier();

  for (int h = 0; h < NH; ++h) {
    const signed char* Ab = &lds[h & 3][0][0];
    const signed char* Bb = &lds[h & 3][1][0];

    // ---- phase A: reads (ks=0) + stage, then barrier/lgkm/MFMA/barrier ----
    i32x4 af0[4], bf0[2];
#pragma unroll
    for (int mi = 0; mi < 4; ++mi) af0[mi] = *(const i32x4*)(Ab + offA[mi] + c0);
#pragma unroll
    for (int ni = 0; ni < 2; ++ni) bf0[ni] = *(const i32x4*)(Bb + offB[ni] + c0);
    if (h + 3 < NH) STAGE(h + 3);   // overwrites buf (h-1)&3: consumed last iter
    __builtin_amdgcn_s_barrier();
    asm volatile("s_waitcnt lgkmcnt(0)" ::: "memory");
    __builtin_amdgcn_s_setprio(1);
#pragma unroll
    for (int mi = 0; mi < 4; ++mi)
#pragma unroll
      for (int ni = 0; ni < 2; ++ni)
        acc[mi][ni] = __builtin_amdgcn_mfma_i32_32x32x32_i8(
            af0[mi], bf0[ni], acc[mi][ni], 0, 0, 0);
    __builtin_amdgcn_s_setprio(0);
    __builtin_amdgcn_s_barrier();

    // ---- phase B: reads (ks=1), then barrier/lgkm/MFMA/vmcnt/barrier ----
    i32x4 af1[4], bf1[2];
#pragma unroll
    for (int mi = 0; mi < 4; ++mi) af1[mi] = *(const i32x4*)(Ab + offA[mi] + c1);
#pragma unroll
    for (int ni = 0; ni < 2; ++ni) bf1[ni] = *(const i32x4*)(Bb + offB[ni] + c1);
    __builtin_amdgcn_s_barrier();
    asm volatile("s_waitcnt lgkmcnt(0)" ::: "memory");
    __builtin_amdgcn_s_setprio(1);
#pragma unroll
    for (int mi = 0; mi < 4; ++mi)
#pragma unroll
      for (int ni = 0; ni < 2; ++ni)
        acc[mi][ni] = __builtin_amdgcn_mfma_i32_32x32x32_i8(
            af1[mi], bf1[ni], acc[mi][ni], 0, 0, 0);
    __builtin_amdgcn_s_setprio(0);

    // retire through half h+1 (needed next iter); keep the rest in flight
    if (h + 3 < NH)      asm volatile("s_waitcnt vmcnt(8)" ::: "memory");
    else if (h + 2 < NH) asm volatile("s_waitcnt vmcnt(4)" ::: "memory");
    else if (h + 1 < NH) asm volatile("s_waitcnt vmcnt(0)" ::: "memory");
    __builtin_amdgcn_s_barrier();
  }
#undef STAGE

  // C/D layout (32x32): col = lane&31, row = (reg&3) + 8*(reg>>2) + 4*(lane>>5)
#pragma unroll
  for (int mi = 0; mi < 4; ++mi) {
    const int rbase = bm + wm + mi * 32 + 4 * fh;
    float ri[16];
#pragma unroll
    for (int r = 0; r < 16; ++r) ri[r] = rowinv[rbase + (r & 3) + 8 * (r >> 2)];
#pragma unroll
    for (int ni = 0; ni < 2; ++ni) {
      const int col = bn + wn + ni * 32 + fl;
#pragma unroll
      for (int r = 0; r < 16; ++r) {
        const int row = rbase + (r & 3) + 8 * (r >> 2);
        C[(size_t)row * N + col] = (float)acc[mi][ni][r] * ri[r];
      }
    }
  }
}

// Safety-net exact fp32 kernel (only if ws_size too small) — slow but correct.
__global__ void naive_k(const float* __restrict__ x, const float* __restrict__ signs,
                        const float* __restrict__ ps, const float* __restrict__ rt,
                        float* __restrict__ out, int M, int N, int K, int P) {
  int idx = blockIdx.x * blockDim.x + threadIdx.x;
  if (idx >= M * N) return;
  int m = idx / N, n = idx % N;
  const float* xr = x + (size_t)m * K;
  const float* wr = signs + (size_t)n * K;
  const int NG = K / 128;
  const size_t G = (size_t)N * NG;
  float acc = 0.f;
  for (int g = 0; g < NG; ++g) {
    float sc = 0.f;
    int gi = n * NG + g;
    for (int p = 0; p < P; ++p) sc += rt[p] * ps[(size_t)p * G + gi];
    float s2 = 0.f;
    for (int kk = 0; kk < 128; ++kk) s2 += xr[g * 128 + kk] * wr[g * 128 + kk];
    acc += sc * s2;
  }
  out[idx] = acc;
}

extern "C" void kernel_launch(void* const* d_in, const int* in_sizes, int n_in,
                              void* d_out, int out_size, void* d_ws, size_t ws_size,
                              hipStream_t stream) {
  const float* x     = (const float*)d_in[0];
  const float* signs = (const float*)d_in[1];
  const float* ps    = (const float*)d_in[2];
  const float* rt    = (const float*)d_in[3];
  float* out = (float*)d_out;

  const int K = 4096, N = 4096, GS = 128;
  const int M = in_sizes[0] / K;   // 8192
  const int G = N / GS * K;        // 131072 flat groups over [N*K]
  const int P = in_sizes[3];       // 8

  const size_t xq_bytes = (size_t)M * K;       // 33.5 MB
  const size_t wq_bytes = (size_t)N * K;       // 16.8 MB
  const size_t ri_bytes = (size_t)M * 4;       // 32 KB
  const size_t need = xq_bytes + wq_bytes + ri_bytes;

  if (ws_size >= need && (M % BM) == 0) {
    signed char* xq = (signed char*)d_ws;
    signed char* wq = (signed char*)((char*)d_ws + xq_bytes);
    float* rowinv   = (float*)((char*)d_ws + xq_bytes + wq_bytes);

    const int NW = N * K / 16 / 256;   // 4096 W-role blocks
    prep_k<<<NW + M, 256, 0, stream>>>(signs, ps, rt, x,
                                       (int4*)wq, (int*)xq, rowinv, G, P, K, NW);

    dim3 grid(N / BN, M / BM);
    gemm_i8_k<<<grid, 512, 0, stream>>>(xq, wq, rowinv, out, M, N, K);
  } else {
    const size_t total = (size_t)M * N;
    naive_k<<<(int)((total + 255) / 256), 256, 0, stream>>>(
        x, signs, ps, rt, out, M, N, K, P);
  }
}

// Round 7
// 421.106 us; speedup vs baseline: 1.1853x; 1.0034x over previous
//
#include <hip/hip_runtime.h>
#include <stdint.h>

#define AS1 __attribute__((address_space(1)))
#define AS3 __attribute__((address_space(3)))

typedef __attribute__((ext_vector_type(4))) int i32x4;
typedef __attribute__((ext_vector_type(16))) int i32x16;

// ---------------- blend: blended[g] = sum_p routing[p] * ps[p*G+g] ----------
__global__ void blend_k(const float* __restrict__ ps, const float* __restrict__ rt,
                        float* __restrict__ blended, int G, int P) {
  int g = blockIdx.x * blockDim.x + threadIdx.x;
  if (g >= G) return;
  float s = 0.f;
  for (int p = 0; p < P; ++p) s += rt[p] * ps[(size_t)p * G + g];
  blended[g] = s;
}

__device__ __forceinline__ int q8(float v, float s) {
  int q = (int)rintf(v * s);
  q = q > 127 ? 127 : q;
  q = q < -127 ? -127 : q;
  return q & 0xff;
}

// ---------------- quantize W: FULLY COALESCED ------------------------------
// One thread per float4 of signs (lane stride 16B -> 16 lines/wave-instr, the
// coalescing ideal) and one packed int store (4B/lane). Group scale
// blended[t>>5] is uniform across 32 consecutive lanes (L1 broadcast).
// Rationale: previous 64B-per-lane layout touched 64 lines per wave-instr on
// the 67MB signs stream (4x the TA/L1 line lookups) -- suspected prep
// bottleneck behind the stable ~257us non-gemm residual.
__global__ __launch_bounds__(256) void quant_w_k(const float4* __restrict__ signs,
                                                 const float* __restrict__ blended,
                                                 int* __restrict__ wq, int n4) {
  int t = blockIdx.x * blockDim.x + threadIdx.x;
  if (t >= n4) return;
  float bl = blended[t >> 5];            // (t*4) >> 7
  int q = (int)rintf(bl * 127.f);
  q = q > 127 ? 127 : q; q = q < 1 ? 1 : q;
  float4 s = signs[t];
  int b0 = (s.x >= 0.f ? q : -q) & 0xff;
  int b1 = (s.y >= 0.f ? q : -q) & 0xff;
  int b2 = (s.z >= 0.f ? q : -q) & 0xff;
  int b3 = (s.w >= 0.f ? q : -q) & 0xff;
  wq[t] = b0 | (b1 << 8) | (b2 << 16) | (b3 << 24);
}

// ---------------- quantize X per row: one block per row (K=4096, 256 thr) ----
// Already coalesced (lane stride 16B on read, 4B on write). Unchanged.
__global__ __launch_bounds__(256) void quant_x_k(const float4* __restrict__ x,
                                                 int* __restrict__ xq,
                                                 float* __restrict__ rowinv, int K) {
  const int m = blockIdx.x;
  const int t = threadIdx.x;
  const int lane = t & 63;
  const int wave = t >> 6;
  const float4* xr = x + (size_t)m * (K / 4);
  float4 v[4];
  float amax = 0.f;
#pragma unroll
  for (int i = 0; i < 4; ++i) {
    v[i] = xr[t + 256 * i];
    amax = fmaxf(amax, fmaxf(fmaxf(fabsf(v[i].x), fabsf(v[i].y)),
                             fmaxf(fabsf(v[i].z), fabsf(v[i].w))));
  }
#pragma unroll
  for (int off = 1; off < 64; off <<= 1)
    amax = fmaxf(amax, __shfl_xor(amax, off));
  __shared__ float red[4];
  if (lane == 0) red[wave] = amax;
  __syncthreads();
  amax = fmaxf(fmaxf(red[0], red[1]), fmaxf(red[2], red[3]));
  const float s = 127.f / amax;
  if (t == 0) rowinv[m] = amax / (127.f * 127.f);
  int* xo = xq + (size_t)m * (K / 4);
#pragma unroll
  for (int i = 0; i < 4; ++i) {
    int p = q8(v[i].x, s) | (q8(v[i].y, s) << 8) | (q8(v[i].z, s) << 16) | (q8(v[i].w, s) << 24);
    xo[t + 256 * i] = p;
  }
}

// ---------------- i8 GEMM: C[M,N] = (A[M,K] * B[N,K]^T) * rowinv[m] ---------
// (round-3/6 best: 165 us, MfmaUtil 36% -- untouched this round)
// 256x256 tile, 8 waves (2Mx4N), per-wave 128x64 via 4x2 of mfma_i32_32x32x32_i8.
// K in 64-byte halves through a 4-deep LDS ring (4 x 32KiB). 2-phase split per
// K-64 with counted vmcnt once per K-64 (never 0 mid-loop). LDS swizzle:
// slot = chunk ^ ((row>>1)&3), applied source-side for the linear
// global_load_lds dest and on the ds_read addr (rule 21).
#define BM 256
#define BN 256

__global__ __launch_bounds__(512, 2) void gemm_i8_k(
    const signed char* __restrict__ A, const signed char* __restrict__ B,
    const float* __restrict__ rowinv, float* __restrict__ C, int M, int N, int K) {
  __shared__ __align__(16) signed char lds[4][2][256 * 64];   // [buf][A/B][row*64+slot*16]
  const int tid  = threadIdx.x;
  const int lane = tid & 63;
  const int wave = tid >> 6;

  // bijective XCD swizzle (nwg = 512, divisible by 8)
  int bid = blockIdx.y * gridDim.x + blockIdx.x;
  const int nwg = gridDim.x * gridDim.y;
  const int cpx = nwg >> 3;
  bid = (bid & 7) * cpx + (bid >> 3);
  const int nbx = N / BN;
  const int bn = (bid % nbx) * BN;
  const int bm = (bid / nbx) * BM;

  const int wm = (wave >> 2) * 128;
  const int wn = (wave & 3) * 64;
  const int fl = lane & 31;
  const int fh = lane >> 5;
  const int sx = (fl >> 1) & 3;   // read-side swizzle: slot = chunk ^ sx

  // loop-invariant LDS read offsets
  int offA[4], offB[2];
#pragma unroll
  for (int mi = 0; mi < 4; ++mi) offA[mi] = (wm + mi * 32 + fl) * 64;
#pragma unroll
  for (int ni = 0; ni < 2; ++ni) offB[ni] = (wn + ni * 32 + fl) * 64;
  const int c0 = ((0 + fh) ^ sx) * 16;   // ks=0 chunk
  const int c1 = ((2 + fh) ^ sx) * 16;   // ks=1 chunk

  i32x16 acc[4][2];
#pragma unroll
  for (int i = 0; i < 4; ++i)
#pragma unroll
    for (int j = 0; j < 2; ++j)
#pragma unroll
      for (int r = 0; r < 16; ++r) acc[i][j][r] = 0;

  // Staging: one global_load_lds = 64 lanes x 16B = 16 rows of 64B (linear
  // dest, lane l -> row R0+(l>>2), slot l&3). Source chunk pre-swizzled:
  // c = (l&3) ^ ((l>>3)&3) so slot s of row r holds chunk s ^ ((r>>1)&3).
  const int sl   = (lane & 3) ^ ((lane >> 3) & 3);
  const int srow = lane >> 2;
  const int rA0 = 16 * (2 * wave + 0) + srow;
  const int rA1 = 16 * (2 * wave + 1) + srow;
  const signed char* gA0 = A + (size_t)(bm + rA0) * K + sl * 16;
  const signed char* gA1 = A + (size_t)(bm + rA1) * K + sl * 16;
  const signed char* gB0 = B + (size_t)(bn + rA0) * K + sl * 16;
  const signed char* gB1 = B + (size_t)(bn + rA1) * K + sl * 16;

#define STAGE(hh)                                                                \
  {                                                                              \
    const int q_  = (hh) & 3;                                                    \
    const int ko_ = (hh) * 64;                                                   \
    __builtin_amdgcn_global_load_lds((AS1 unsigned int*)(gA0 + ko_),             \
        (AS3 unsigned int*)(&lds[q_][0][(2 * wave + 0) * 1024]), 16, 0, 0);      \
    __builtin_amdgcn_global_load_lds((AS1 unsigned int*)(gA1 + ko_),             \
        (AS3 unsigned int*)(&lds[q_][0][(2 * wave + 1) * 1024]), 16, 0, 0);      \
    __builtin_amdgcn_global_load_lds((AS1 unsigned int*)(gB0 + ko_),             \
        (AS3 unsigned int*)(&lds[q_][1][(2 * wave + 0) * 1024]), 16, 0, 0);      \
    __builtin_amdgcn_global_load_lds((AS1 unsigned int*)(gB1 + ko_),             \
        (AS3 unsigned int*)(&lds[q_][1][(2 * wave + 1) * 1024]), 16, 0, 0);      \
  }

  const int NH = K >> 6;   // 64-byte halves of K
  STAGE(0); STAGE(1); STAGE(2);
  asm volatile("s_waitcnt vmcnt(8)" ::: "memory");   // half 0 resident
  __builtin_amdgcn_s_barrier();

  for (int h = 0; h < NH; ++h) {
    const signed char* Ab = &lds[h & 3][0][0];
    const signed char* Bb = &lds[h & 3][1][0];

    // ---- phase A: reads (ks=0) + stage, then barrier/lgkm/MFMA/barrier ----
    i32x4 af0[4], bf0[2];
#pragma unroll
    for (int mi = 0; mi < 4; ++mi) af0[mi] = *(const i32x4*)(Ab + offA[mi] + c0);
#pragma unroll
    for (int ni = 0; ni < 2; ++ni) bf0[ni] = *(const i32x4*)(Bb + offB[ni] + c0);
    if (h + 3 < NH) STAGE(h + 3);   // overwrites buf (h-1)&3: consumed last iter
    __builtin_amdgcn_s_barrier();
    asm volatile("s_waitcnt lgkmcnt(0)" ::: "memory");
    __builtin_amdgcn_s_setprio(1);
#pragma unroll
    for (int mi = 0; mi < 4; ++mi)
#pragma unroll
      for (int ni = 0; ni < 2; ++ni)
        acc[mi][ni] = __builtin_amdgcn_mfma_i32_32x32x32_i8(
            af0[mi], bf0[ni], acc[mi][ni], 0, 0, 0);
    __builtin_amdgcn_s_setprio(0);
    __builtin_amdgcn_s_barrier();

    // ---- phase B: reads (ks=1), then barrier/lgkm/MFMA/vmcnt/barrier ----
    i32x4 af1[4], bf1[2];
#pragma unroll
    for (int mi = 0; mi < 4; ++mi) af1[mi] = *(const i32x4*)(Ab + offA[mi] + c1);
#pragma unroll
    for (int ni = 0; ni < 2; ++ni) bf1[ni] = *(const i32x4*)(Bb + offB[ni] + c1);
    __builtin_amdgcn_s_barrier();
    asm volatile("s_waitcnt lgkmcnt(0)" ::: "memory");
    __builtin_amdgcn_s_setprio(1);
#pragma unroll
    for (int mi = 0; mi < 4; ++mi)
#pragma unroll
      for (int ni = 0; ni < 2; ++ni)
        acc[mi][ni] = __builtin_amdgcn_mfma_i32_32x32x32_i8(
            af1[mi], bf1[ni], acc[mi][ni], 0, 0, 0);
    __builtin_amdgcn_s_setprio(0);

    // retire through half h+1 (needed next iter); keep the rest in flight
    if (h + 3 < NH)      asm volatile("s_waitcnt vmcnt(8)" ::: "memory");
    else if (h + 2 < NH) asm volatile("s_waitcnt vmcnt(4)" ::: "memory");
    else if (h + 1 < NH) asm volatile("s_waitcnt vmcnt(0)" ::: "memory");
    __builtin_amdgcn_s_barrier();
  }
#undef STAGE

  // C/D layout (32x32): col = lane&31, row = (reg&3) + 8*(reg>>2) + 4*(lane>>5)
#pragma unroll
  for (int mi = 0; mi < 4; ++mi) {
    const int rbase = bm + wm + mi * 32 + 4 * fh;
    float ri[16];
#pragma unroll
    for (int r = 0; r < 16; ++r) ri[r] = rowinv[rbase + (r & 3) + 8 * (r >> 2)];
#pragma unroll
    for (int ni = 0; ni < 2; ++ni) {
      const int col = bn + wn + ni * 32 + fl;
#pragma unroll
      for (int r = 0; r < 16; ++r) {
        const int row = rbase + (r & 3) + 8 * (r >> 2);
        C[(size_t)row * N + col] = (float)acc[mi][ni][r] * ri[r];
      }
    }
  }
}

// Safety-net exact fp32 kernel (only if ws_size too small) — slow but correct.
__global__ void naive_k(const float* __restrict__ x, const float* __restrict__ signs,
                        const float* __restrict__ ps, const float* __restrict__ rt,
                        float* __restrict__ out, int M, int N, int K, int P) {
  int idx = blockIdx.x * blockDim.x + threadIdx.x;
  if (idx >= M * N) return;
  int m = idx / N, n = idx % N;
  const float* xr = x + (size_t)m * K;
  const float* wr = signs + (size_t)n * K;
  const int NG = K / 128;
  const size_t G = (size_t)N * NG;
  float acc = 0.f;
  for (int g = 0; g < NG; ++g) {
    float sc = 0.f;
    int gi = n * NG + g;
    for (int p = 0; p < P; ++p) sc += rt[p] * ps[(size_t)p * G + gi];
    float s2 = 0.f;
    for (int kk = 0; kk < 128; ++kk) s2 += xr[g * 128 + kk] * wr[g * 128 + kk];
    acc += sc * s2;
  }
  out[idx] = acc;
}

extern "C" void kernel_launch(void* const* d_in, const int* in_sizes, int n_in,
                              void* d_out, int out_size, void* d_ws, size_t ws_size,
                              hipStream_t stream) {
  const float* x     = (const float*)d_in[0];
  const float* signs = (const float*)d_in[1];
  const float* ps    = (const float*)d_in[2];
  const float* rt    = (const float*)d_in[3];
  float* out = (float*)d_out;

  const int K = 4096, N = 4096, GS = 128;
  const int M = in_sizes[0] / K;   // 8192
  const int G = N / GS * K;        // 131072 flat groups over [N*K]
  const int P = in_sizes[3];       // 8

  const size_t xq_bytes = (size_t)M * K;       // 33.5 MB
  const size_t wq_bytes = (size_t)N * K;       // 16.8 MB
  const size_t bl_bytes = (size_t)G * 4;       // 0.5 MB
  const size_t ri_bytes = (size_t)M * 4;       // 32 KB
  const size_t need = xq_bytes + wq_bytes + bl_bytes + ri_bytes;

  if (ws_size >= need && (M % BM) == 0) {
    signed char* xq = (signed char*)d_ws;
    signed char* wq = (signed char*)((char*)d_ws + xq_bytes);
    float* blended  = (float*)((char*)d_ws + xq_bytes + wq_bytes);
    float* rowinv   = (float*)((char*)d_ws + xq_bytes + wq_bytes + bl_bytes);

    blend_k<<<(G + 255) / 256, 256, 0, stream>>>(ps, rt, blended, G, P);

    const int n4w = N * K / 4;
    quant_w_k<<<(n4w + 255) / 256, 256, 0, stream>>>(
        (const float4*)signs, blended, (int*)wq, n4w);

    quant_x_k<<<M, 256, 0, stream>>>((const float4*)x, (int*)xq, rowinv, K);

    dim3 grid(N / BN, M / BM);
    gemm_i8_k<<<grid, 512, 0, stream>>>(xq, wq, rowinv, out, M, N, K);
  } else {
    const size_t total = (size_t)M * N;
    naive_k<<<(int)((total + 255) / 256), 256, 0, stream>>>(
        x, signs, ps, rt, out, M, N, K, P);
  }
}